// Round 19
// baseline (149.473 us; speedup 1.0000x reference)
//
#include <hip/hip_runtime.h>

#define BB 2
#define HH 48
#define WW 48
#define CC 192
#define NHEADS 6
#define HD 32
#define KK 9
#define FF 486
#define NPIX (BB*HH*WW)   // 4608
#define SCALE 0.17677669529663687f  // 1/sqrt(32)

typedef __bf16 bf16;
typedef __attribute__((ext_vector_type(4))) __bf16 bf16x4;
typedef __attribute__((ext_vector_type(8))) __bf16 bf16x8;
typedef __attribute__((ext_vector_type(4))) float f32x4;

#define KD 192
#define LDA 200   // padded LDS row stride in bf16 (400 B)

// ---------------------------------------------------------------------------
// gemm_va: 64x64 tiles, grid (72, 11) = 792 blocks.  (identical to round 11)
// v = x@vw^T -> bf16 out;  a = x@aw^T + ab -> fp32 out.
// ---------------------------------------------------------------------------
__global__ __launch_bounds__(256) void gemm_va_kernel(
    const float* __restrict__ x, const float* __restrict__ vw,
    const float* __restrict__ aw, const float* __restrict__ ab,
    bf16* __restrict__ v, float* __restrict__ a)
{
    __shared__ bf16 As[64][LDA];
    __shared__ bf16 Bs[64][LDA];
    const int t = threadIdx.x;
    const int m0 = blockIdx.x * 64;
    const int by = blockIdx.y;
    const bool is_v = (by < 3);
    const int n0 = is_v ? by * 64 : (by - 3) * 64;
    const int Ndim = is_v ? CC : FF;
    const float* W = is_v ? vw : aw;

    #pragma unroll
    for (int i = 0; i < 12; ++i) {
        const int f = t + i * 256;
        const int row = f / 48, c4 = f % 48;
        const float4 xv = *(const float4*)(x + (size_t)(m0 + row) * KD + c4 * 4);
        bf16x4 tv = { (__bf16)xv.x, (__bf16)xv.y, (__bf16)xv.z, (__bf16)xv.w };
        *(bf16x4*)(&As[row][c4 * 4]) = tv;
    }
    #pragma unroll
    for (int i = 0; i < 12; ++i) {
        const int f = t + i * 256;
        const int row = f / 48, c4 = f % 48;
        float4 wv = make_float4(0.f, 0.f, 0.f, 0.f);
        if (n0 + row < Ndim)
            wv = *(const float4*)(W + (size_t)(n0 + row) * KD + c4 * 4);
        bf16x4 tv = { (__bf16)wv.x, (__bf16)wv.y, (__bf16)wv.z, (__bf16)wv.w };
        *(bf16x4*)(&Bs[row][c4 * 4]) = tv;
    }
    __syncthreads();

    const int wave = t >> 6, lane = t & 63;
    const int wm = (wave >> 1) * 32;
    const int wn = (wave & 1) * 32;
    const int lrow = lane & 15;
    const int lk   = (lane >> 4) * 8;

    f32x4 acc[2][2] = {};
    #pragma unroll
    for (int ks = 0; ks < 6; ++ks) {
        bf16x8 afr[2], bfr[2];
        #pragma unroll
        for (int j = 0; j < 2; ++j) {
            afr[j] = *(const bf16x8*)(&As[wm + j * 16 + lrow][ks * 32 + lk]);
            bfr[j] = *(const bf16x8*)(&Bs[wn + j * 16 + lrow][ks * 32 + lk]);
        }
        #pragma unroll
        for (int i = 0; i < 2; ++i)
            #pragma unroll
            for (int j = 0; j < 2; ++j)
                acc[i][j] = __builtin_amdgcn_mfma_f32_16x16x32_bf16(afr[i], bfr[j], acc[i][j], 0, 0, 0);
    }

    const int crow = (lane >> 4) * 4;
    if (is_v) {
        #pragma unroll
        for (int j = 0; j < 2; ++j) {
            const int col = n0 + wn + j * 16 + lrow;   // < 192 always
            #pragma unroll
            for (int i = 0; i < 2; ++i)
                #pragma unroll
                for (int r = 0; r < 4; ++r) {
                    const int row = m0 + wm + i * 16 + crow + r;
                    v[(size_t)row * CC + col] = (__bf16)acc[i][j][r];
                }
        }
    } else {
        #pragma unroll
        for (int j = 0; j < 2; ++j) {
            const int col = n0 + wn + j * 16 + lrow;
            if (col < FF) {
                const float bv = ab[col];
                #pragma unroll
                for (int i = 0; i < 2; ++i)
                    #pragma unroll
                    for (int r = 0; r < 4; ++r) {
                        const int row = m0 + wm + i * 16 + crow + r;
                        a[(size_t)row * FF + col] = acc[i][j][r] + bv;
                    }
            }
        }
    }
}

// ---------------------------------------------------------------------------
// attn_fold (gather form, no atomics): one 192-thread block per OUTPUT pixel.
// folded[y,x,c] = sum_i sum_j p_{nbr(i)}[head, i, j] * v[y + j/3-i/3, x + j%3-i%3, c]
// where nbr(i) = (y+1-i/3, x+1-i%3). Re-runs neighbors' softmaxes (cheap).
// ---------------------------------------------------------------------------
__global__ void attn_fold_kernel(const bf16* __restrict__ v,
                                 const float* __restrict__ a,
                                 bf16* __restrict__ folded) {
    const int n = blockIdx.x;
    const int tid = threadIdx.x;  // 0..191
    const int b = n / (HH * WW), rem = n % (HH * WW), y = rem / WW, x = rem % WW;

    __shared__ float p[KK][FF];        // 9 neighbors' attention maps (17.5 KB)
    __shared__ float vl[5][5][CC];     // 5x5 v patch, fp32 (19.2 KB)

    // stage v patch: 25 rows, zero-padded at borders
    #pragma unroll
    for (int r = 0; r < 25; ++r) {
        const int gy = y + r / 5 - 2, gx = x + r % 5 - 2;
        float val = 0.f;
        if (gy >= 0 && gy < HH && gx >= 0 && gx < WW)
            val = (float)v[((size_t)(b * HH + gy) * WW + gx) * CC + tid];
        vl[r / 5][r % 5][tid] = val;
    }
    // stage 9 neighbors' logits (skip out-of-image neighbors; left as garbage, unused)
    #pragma unroll
    for (int i = 0; i < KK; ++i) {
        const int ny = y + 1 - i / 3, nx = x + 1 - i % 3;
        if (ny >= 0 && ny < HH && nx >= 0 && nx < WW) {
            const float* an = a + ((size_t)(b * HH + ny) * WW + nx) * FF;
            for (int f = tid; f < FF; f += CC) p[i][f] = an[f];
        }
    }
    __syncthreads();

    // softmax: 9 neighbors x 54 rows of 9
    for (int r = tid; r < KK * 54; r += CC) {
        const int i = r / 54, hr = r % 54;
        const int ny = y + 1 - i / 3, nx = x + 1 - i % 3;
        if (ny < 0 || ny >= HH || nx < 0 || nx >= WW) continue;
        float* row = &p[i][hr * 9];
        float t[KK];
        float m = -1e30f;
        #pragma unroll
        for (int j = 0; j < KK; ++j) { t[j] = row[j] * SCALE; m = fmaxf(m, t[j]); }
        float s = 0.f;
        #pragma unroll
        for (int j = 0; j < KK; ++j) { t[j] = __expf(t[j] - m); s += t[j]; }
        const float inv = 1.f / s;
        #pragma unroll
        for (int j = 0; j < KK; ++j) row[j] = t[j] * inv;
    }
    __syncthreads();

    // accumulate folded value for this pixel, channel = tid
    const int head = tid / HD;
    float acc = 0.f;
    #pragma unroll
    for (int i = 0; i < KK; ++i) {
        const int ny = y + 1 - i / 3, nx = x + 1 - i % 3;
        if (ny < 0 || ny >= HH || nx < 0 || nx >= WW) continue;
        const float* pn = &p[i][head * 81 + i * 9];   // tap i of neighbor i
        const int di = i / 3, dj = i % 3;
        #pragma unroll
        for (int j = 0; j < KK; ++j)
            acc += pn[j] * vl[j / 3 - di + 2][j % 3 - dj + 2][tid];
    }
    folded[(size_t)n * CC + tid] = (__bf16)acc;
}

// ---------------------------------------------------------------------------
// proj: BM=32, grid (144, 3) = 432 blocks. A = straight bf16 copy from folded.
// (identical to round 11)
// ---------------------------------------------------------------------------
__global__ __launch_bounds__(256) void proj_kernel(
    const bf16* __restrict__ folded, const float* __restrict__ pw,
    const float* __restrict__ pb, float* __restrict__ out)
{
    __shared__ bf16 As[32][LDA];
    __shared__ bf16 Bs[64][LDA];
    const int t = threadIdx.x;
    const int m0 = blockIdx.x * 32;
    const int n0 = blockIdx.y * 64;

    // stage A: 32 rows x 24 chunks of bf16x8, 3 per thread
    #pragma unroll
    for (int i = 0; i < 3; ++i) {
        const int f = t + i * 256;
        const int row = f / 24, c8 = f % 24;
        const bf16x8 av = *(const bf16x8*)(folded + (size_t)(m0 + row) * KD + c8 * 8);
        *(bf16x8*)(&As[row][c8 * 8]) = av;
    }
    // stage B: 64 rows x 48 float4, 12 per thread
    #pragma unroll
    for (int i = 0; i < 12; ++i) {
        const int f = t + i * 256;
        const int row = f / 48, c4 = f % 48;
        const float4 wv = *(const float4*)(pw + (size_t)(n0 + row) * KD + c4 * 4);
        bf16x4 tv = { (__bf16)wv.x, (__bf16)wv.y, (__bf16)wv.z, (__bf16)wv.w };
        *(bf16x4*)(&Bs[row][c4 * 4]) = tv;
    }
    __syncthreads();

    const int wave = t >> 6, lane = t & 63;
    const int wm = (wave & 1) * 16;     // 0/16
    const int wn = (wave >> 1) * 32;    // 0/32
    const int lrow = lane & 15;
    const int lk   = (lane >> 4) * 8;

    f32x4 acc[2] = {};
    #pragma unroll
    for (int ks = 0; ks < 6; ++ks) {
        bf16x8 afr = *(const bf16x8*)(&As[wm + lrow][ks * 32 + lk]);
        #pragma unroll
        for (int j = 0; j < 2; ++j) {
            bf16x8 bfr = *(const bf16x8*)(&Bs[wn + j * 16 + lrow][ks * 32 + lk]);
            acc[j] = __builtin_amdgcn_mfma_f32_16x16x32_bf16(afr, bfr, acc[j], 0, 0, 0);
        }
    }

    const int crow = (lane >> 4) * 4;
    #pragma unroll
    for (int j = 0; j < 2; ++j) {
        const int col = n0 + wn + j * 16 + lrow;   // < 192 always
        const float bv = pb[col];
        #pragma unroll
        for (int r = 0; r < 4; ++r) {
            const int row = m0 + wm + crow + r;
            out[(size_t)row * CC + col] = acc[j][r] + bv;
        }
    }
}

extern "C" void kernel_launch(void* const* d_in, const int* in_sizes, int n_in,
                              void* d_out, int out_size, void* d_ws, size_t ws_size,
                              hipStream_t stream) {
    const float* x   = (const float*)d_in[0];
    const float* vw  = (const float*)d_in[1];
    const float* aw  = (const float*)d_in[2];
    const float* ab  = (const float*)d_in[3];
    const float* pw  = (const float*)d_in[4];
    const float* pb  = (const float*)d_in[5];
    float* out = (float*)d_out;

    // ws layout: a (fp32), v (bf16), folded (bf16) — no o, no atomics, no memset
    float* a      = (float*)d_ws;                          // NPIX*FF fp32
    bf16* v       = (bf16*)(a + (size_t)NPIX * FF);        // NPIX*CC bf16
    bf16* folded  = v + (size_t)NPIX * CC;                 // NPIX*CC bf16

    dim3 blk(256);
    dim3 grid_va(NPIX / 64, 3 + 8);          // 72 x 11 = 792 blocks
    dim3 grid_pj(NPIX / 32, CC / 64);        // 144 x 3 = 432 blocks

    gemm_va_kernel<<<grid_va, blk, 0, stream>>>(x, vw, aw, ab, v, a);
    attn_fold_kernel<<<NPIX, CC, 0, stream>>>(v, a, folded);
    proj_kernel<<<grid_pj, blk, 0, stream>>>(folded, pw, pb, out);
}

// Round 20
// 102.735 us; speedup vs baseline: 1.4549x; 1.4549x over previous
//
#include <hip/hip_runtime.h>

#define BB 2
#define HH 48
#define WW 48
#define CC 192
#define NHEADS 6
#define HD 32
#define KK 9
#define FF 486
#define NPIX (BB*HH*WW)   // 4608
#define SCALE 0.17677669529663687f  // 1/sqrt(32)

typedef __bf16 bf16;
typedef __attribute__((ext_vector_type(2))) __bf16 bf16x2;
typedef __attribute__((ext_vector_type(4))) __bf16 bf16x4;
typedef __attribute__((ext_vector_type(8))) __bf16 bf16x8;
typedef __attribute__((ext_vector_type(4))) float f32x4;

#define KD 192
#define LDA 200   // padded LDS row stride in bf16 (400 B)

// float4 chunk counts for the one-shot fp32->bf16 conversion
#define X_F4  221184   // 884736/4
#define VW_F4 9216
#define AW_F4 23328
#define PW_F4 9216
#define TOT_F4 (X_F4 + VW_F4 + AW_F4 + PW_F4)   // 262944

// ---------------------------------------------------------------------------
// cvt: one-shot fp32 -> bf16 of x, vw, aw, pw into contiguous ws buffer.
// ---------------------------------------------------------------------------
__global__ void cvt_kernel(const float* __restrict__ x, const float* __restrict__ vw,
                           const float* __restrict__ aw, const float* __restrict__ pw,
                           bf16* __restrict__ outb) {
    const int idx = blockIdx.x * blockDim.x + threadIdx.x;
    if (idx >= TOT_F4) return;
    const float* src; int off;
    if (idx < X_F4)                         { src = x;  off = idx; }
    else if (idx < X_F4 + VW_F4)            { src = vw; off = idx - X_F4; }
    else if (idx < X_F4 + VW_F4 + AW_F4)    { src = aw; off = idx - X_F4 - VW_F4; }
    else                                    { src = pw; off = idx - X_F4 - VW_F4 - AW_F4; }
    const float4 v4 = *(const float4*)(src + (size_t)off * 4);
    bf16x4 t = { (__bf16)v4.x, (__bf16)v4.y, (__bf16)v4.z, (__bf16)v4.w };
    *(bf16x4*)(outb + (size_t)idx * 4) = t;
}

// ---------------------------------------------------------------------------
// gemm_va: 64x64 tiles, grid (72, 11) = 792 blocks, all-bf16 staging.
// v = x@vw^T -> bf16;  a = x@aw^T + ab -> bf16.
// ---------------------------------------------------------------------------
__global__ __launch_bounds__(256) void gemm_va_kernel(
    const bf16* __restrict__ xb, const bf16* __restrict__ vwb,
    const bf16* __restrict__ awb, const float* __restrict__ ab,
    bf16* __restrict__ v, bf16* __restrict__ a)
{
    __shared__ bf16 As[64][LDA];
    __shared__ bf16 Bs[64][LDA];
    const int t = threadIdx.x;
    const int m0 = blockIdx.x * 64;
    const int by = blockIdx.y;
    const bool is_v = (by < 3);
    const int n0 = is_v ? by * 64 : (by - 3) * 64;
    const int Ndim = is_v ? CC : FF;
    const bf16* W = is_v ? vwb : awb;

    // stage A: 64 rows x 24 bf16x8 chunks, 6 per thread (direct copy)
    #pragma unroll
    for (int i = 0; i < 6; ++i) {
        const int f = t + i * 256;
        const int row = f / 24, c8 = f % 24;
        *(bf16x8*)(&As[row][c8 * 8]) =
            *(const bf16x8*)(xb + (size_t)(m0 + row) * KD + c8 * 8);
    }
    // stage B: 6 chunks per thread with row guard (FF tail)
    #pragma unroll
    for (int i = 0; i < 6; ++i) {
        const int f = t + i * 256;
        const int row = f / 24, c8 = f % 24;
        bf16x8 wv;
        #pragma unroll
        for (int z = 0; z < 8; ++z) wv[z] = (__bf16)0.f;
        if (n0 + row < Ndim)
            wv = *(const bf16x8*)(W + (size_t)(n0 + row) * KD + c8 * 8);
        *(bf16x8*)(&Bs[row][c8 * 8]) = wv;
    }
    __syncthreads();

    const int wave = t >> 6, lane = t & 63;
    const int wm = (wave >> 1) * 32;
    const int wn = (wave & 1) * 32;
    const int lrow = lane & 15;
    const int lk   = (lane >> 4) * 8;

    f32x4 acc[2][2] = {};
    #pragma unroll
    for (int ks = 0; ks < 6; ++ks) {
        bf16x8 afr[2], bfr[2];
        #pragma unroll
        for (int j = 0; j < 2; ++j) {
            afr[j] = *(const bf16x8*)(&As[wm + j * 16 + lrow][ks * 32 + lk]);
            bfr[j] = *(const bf16x8*)(&Bs[wn + j * 16 + lrow][ks * 32 + lk]);
        }
        #pragma unroll
        for (int i = 0; i < 2; ++i)
            #pragma unroll
            for (int j = 0; j < 2; ++j)
                acc[i][j] = __builtin_amdgcn_mfma_f32_16x16x32_bf16(afr[i], bfr[j], acc[i][j], 0, 0, 0);
    }

    const int crow = (lane >> 4) * 4;
    if (is_v) {
        #pragma unroll
        for (int j = 0; j < 2; ++j) {
            const int col = n0 + wn + j * 16 + lrow;   // < 192 always
            #pragma unroll
            for (int i = 0; i < 2; ++i)
                #pragma unroll
                for (int r = 0; r < 4; ++r) {
                    const int row = m0 + wm + i * 16 + crow + r;
                    v[(size_t)row * CC + col] = (__bf16)acc[i][j][r];
                }
        }
    } else {
        #pragma unroll
        for (int j = 0; j < 2; ++j) {
            const int col = n0 + wn + j * 16 + lrow;
            if (col < FF) {
                const float bv = ab[col];
                #pragma unroll
                for (int i = 0; i < 2; ++i)
                    #pragma unroll
                    for (int r = 0; r < 4; ++r) {
                        const int row = m0 + wm + i * 16 + crow + r;
                        a[(size_t)row * FF + col] = (__bf16)(acc[i][j][r] + bv);
                    }
            }
        }
    }
}

// ---------------------------------------------------------------------------
// attn: one 192-thread block per pixel (round-11 structure; a now bf16).
// ---------------------------------------------------------------------------
__global__ void attn_kernel(const bf16* __restrict__ v, const bf16* __restrict__ a,
                            bf16* __restrict__ o) {
    int n = blockIdx.x;
    int tid = threadIdx.x; // 0..191
    int b = n / (HH * WW), rem = n % (HH * WW), h = rem / WW, w = rem % WW;
    __shared__ float p[FF];
    __shared__ float vl[KK][CC];

    for (int f = tid; f < FF; f += CC) p[f] = (float)a[(size_t)n * FF + f];
    #pragma unroll
    for (int j = 0; j < KK; ++j) {
        int hh = h + j / 3 - 1, ww = w + j % 3 - 1;
        if (hh >= 0 && hh < HH && ww >= 0 && ww < WW)
            vl[j][tid] = (float)v[((size_t)(b * HH + hh) * WW + ww) * CC + tid];
        else
            vl[j][tid] = 0.f;
    }
    __syncthreads();

    if (tid < NHEADS * KK) {
        float* row = p + tid * KK;
        float t[KK];
        float m = -1e30f;
        #pragma unroll
        for (int j = 0; j < KK; ++j) { t[j] = row[j] * SCALE; m = fmaxf(m, t[j]); }
        float s = 0.f;
        #pragma unroll
        for (int j = 0; j < KK; ++j) { t[j] = __expf(t[j] - m); s += t[j]; }
        float inv = 1.f / s;
        #pragma unroll
        for (int j = 0; j < KK; ++j) row[j] = t[j] * inv;
    }
    __syncthreads();

    int head = tid / HD;
    const float* ph = p + head * 81;
    #pragma unroll
    for (int i = 0; i < KK; ++i) {
        float acc = 0.f;
        #pragma unroll
        for (int j = 0; j < KK; ++j) acc += ph[i * 9 + j] * vl[j][tid];
        o[((size_t)n * KK + i) * CC + tid] = (__bf16)acc;
    }
}

// ---------------------------------------------------------------------------
// fold: linear, 2 channels (bf16x2) per thread. grid 1728 x 256. (round-11)
// ---------------------------------------------------------------------------
__global__ void fold_kernel(const bf16x2* __restrict__ o, bf16x2* __restrict__ folded) {
    const int idx = blockIdx.x * blockDim.x + threadIdx.x;   // NPIX*96
    const int c2 = idx % 96, n = idx / 96;
    const int b = n / (HH * WW), rem = n % (HH * WW), y = rem / WW, x = rem % WW;
    float s0 = 0.f, s1 = 0.f;
    #pragma unroll
    for (int ki = 0; ki < 3; ++ki) {
        const int gy = y + 1 - ki;
        if (gy < 0 || gy >= HH) continue;
        #pragma unroll
        for (int kj = 0; kj < 3; ++kj) {
            const int gx = x + 1 - kj;
            if (gx < 0 || gx >= WW) continue;
            const size_t ps = (size_t)(b * HH + gy) * WW + gx;
            const bf16x2 ov = o[(ps * KK + ki * 3 + kj) * 96 + c2];
            s0 += (float)ov.x; s1 += (float)ov.y;
        }
    }
    bf16x2 r = { (__bf16)s0, (__bf16)s1 };
    folded[(size_t)n * 96 + c2] = r;
}

// ---------------------------------------------------------------------------
// proj: 64x64 tiles, grid (72, 3) = 216 blocks, all-bf16 staging.
// ---------------------------------------------------------------------------
__global__ __launch_bounds__(256) void proj_kernel(
    const bf16* __restrict__ folded, const bf16* __restrict__ pwb,
    const float* __restrict__ pb, float* __restrict__ out)
{
    __shared__ bf16 As[64][LDA];
    __shared__ bf16 Bs[64][LDA];
    const int t = threadIdx.x;
    const int m0 = blockIdx.x * 64;
    const int n0 = blockIdx.y * 64;

    #pragma unroll
    for (int i = 0; i < 6; ++i) {
        const int f = t + i * 256;
        const int row = f / 24, c8 = f % 24;
        *(bf16x8*)(&As[row][c8 * 8]) =
            *(const bf16x8*)(folded + (size_t)(m0 + row) * KD + c8 * 8);
    }
    #pragma unroll
    for (int i = 0; i < 6; ++i) {
        const int f = t + i * 256;
        const int row = f / 24, c8 = f % 24;   // n0+row <= 191, always in bounds
        *(bf16x8*)(&Bs[row][c8 * 8]) =
            *(const bf16x8*)(pwb + (size_t)(n0 + row) * KD + c8 * 8);
    }
    __syncthreads();

    const int wave = t >> 6, lane = t & 63;
    const int wm = (wave >> 1) * 32;
    const int wn = (wave & 1) * 32;
    const int lrow = lane & 15;
    const int lk   = (lane >> 4) * 8;

    f32x4 acc[2][2] = {};
    #pragma unroll
    for (int ks = 0; ks < 6; ++ks) {
        bf16x8 afr[2], bfr[2];
        #pragma unroll
        for (int j = 0; j < 2; ++j) {
            afr[j] = *(const bf16x8*)(&As[wm + j * 16 + lrow][ks * 32 + lk]);
            bfr[j] = *(const bf16x8*)(&Bs[wn + j * 16 + lrow][ks * 32 + lk]);
        }
        #pragma unroll
        for (int i = 0; i < 2; ++i)
            #pragma unroll
            for (int j = 0; j < 2; ++j)
                acc[i][j] = __builtin_amdgcn_mfma_f32_16x16x32_bf16(afr[i], bfr[j], acc[i][j], 0, 0, 0);
    }

    const int crow = (lane >> 4) * 4;
    #pragma unroll
    for (int j = 0; j < 2; ++j) {
        const int col = n0 + wn + j * 16 + lrow;   // < 192 always
        const float bv = pb[col];
        #pragma unroll
        for (int i = 0; i < 2; ++i)
            #pragma unroll
            for (int r = 0; r < 4; ++r) {
                const int row = m0 + wm + i * 16 + crow + r;
                out[(size_t)row * CC + col] = acc[i][j][r] + bv;
            }
    }
}

extern "C" void kernel_launch(void* const* d_in, const int* in_sizes, int n_in,
                              void* d_out, int out_size, void* d_ws, size_t ws_size,
                              hipStream_t stream) {
    const float* x   = (const float*)d_in[0];
    const float* vw  = (const float*)d_in[1];
    const float* aw  = (const float*)d_in[2];
    const float* ab  = (const float*)d_in[3];
    const float* pw  = (const float*)d_in[4];
    const float* pb  = (const float*)d_in[5];
    float* out = (float*)d_out;

    // ws layout (all bf16): a, o, folded, conv(x|vw|aw|pw), v
    bf16* a      = (bf16*)d_ws;                      // NPIX*FF
    bf16* o      = a + (size_t)NPIX * FF;            // NPIX*KK*CC
    bf16* folded = o + (size_t)NPIX * KK * CC;       // NPIX*CC
    bf16* conv   = folded + (size_t)NPIX * CC;       // 1051776
    bf16* xb     = conv;
    bf16* vwb    = conv + 884736;
    bf16* awb    = vwb + 36864;
    bf16* pwb    = awb + 93312;
    bf16* v      = pwb + 36864;                      // NPIX*CC

    dim3 blk(256);
    dim3 grid_va(NPIX / 64, 3 + 8);          // 72 x 11 = 792 blocks
    dim3 grid_pj(NPIX / 64, CC / 64);        // 72 x 3  = 216 blocks

    cvt_kernel<<<(TOT_F4 + 255) / 256, blk, 0, stream>>>(x, vw, aw, pw, conv);
    gemm_va_kernel<<<grid_va, blk, 0, stream>>>(xb, vwb, awb, ab, v, a);
    attn_kernel<<<NPIX, CC, 0, stream>>>(v, a, o);
    fold_kernel<<<(NPIX * 96) / 256, blk, 0, stream>>>((const bf16x2*)o, (bf16x2*)folded);
    proj_kernel<<<grid_pj, blk, 0, stream>>>(folded, pwb, pb, out);
}